// Round 16
// baseline (191.886 us; speedup 1.0000x reference)
//
#include <hip/hip_runtime.h>
#include <hip/hip_bf16.h>

typedef __hip_bfloat16 bf16;
typedef unsigned short u16;
typedef unsigned int u32;
typedef unsigned long long u64;
typedef float f32x4 __attribute__((ext_vector_type(4)));
typedef short s16x8 __attribute__((ext_vector_type(8)));
typedef unsigned short u16x4 __attribute__((ext_vector_type(4)));

static constexpr int SQ    = 512;
static constexpr int BB    = 16;
static constexpr int HH    = 1024;
static constexpr int NHEAD = 16;
static constexpr int ROWS  = SQ * BB;        // 8192
static constexpr int QKVC  = 3 * HH;         // 3072

// ---- ws layout (bytes) ----
static constexpr long long OFF_M16   = 4096;     // 512KB expanded mask
static constexpr long long OFF_WQT   = 1048576;
static constexpr long long OFF_WOT   = OFF_WQT + (long long)QKVC * HH * 2;
static constexpr long long OFF_QK    = OFF_WOT + (long long)HH * HH * 2;
static constexpr long long OFF_VT    = OFF_QK + (long long)ROWS * 2048 * 2;
static constexpr long long OFF_CTX   = OFF_VT + (long long)256 * 64 * 512 * 2;

__device__ __forceinline__ float load_f(const void* p, long long i, int is_bf16) {
  if (is_bf16) return __bfloat162float(((const bf16*)p)[i]);
  return ((const float*)p)[i];
}
__device__ __forceinline__ u16 f2b(float x) { bf16 h = __float2bfloat16(x); return *(u16*)&h; }
__device__ __forceinline__ f32x4 mfma_bf16(s16x8 a, s16x8 b, f32x4 c) {
  return __builtin_amdgcn_mfma_f32_16x16x32_bf16(a, b, c, 0, 0, 0);
}
__device__ __forceinline__ void gll16(const void* g, void* lds) {
  __builtin_amdgcn_global_load_lds((const __attribute__((address_space(1))) unsigned int*)g,
                                   (__attribute__((address_space(3))) unsigned int*)lds, 16, 0, 0);
}
__device__ __forceinline__ u32 cvtpk(float lo, float hi) {
  u32 r;
  asm volatile("v_cvt_pk_bf16_f32 %0, %1, %2" : "=v"(r) : "v"(lo), "v"(hi));
  return r;
}
// bijective XCD-aware block swizzle (live-verified r6-r15)
__device__ __forceinline__ void xcd_swz(int& bx, int& by) {
  int gx = gridDim.x;
  int nw = gx * gridDim.y;
  int lin = by * gx + bx;
  int q = nw >> 3;
  int nl = (lin & 7) * q + (lin >> 3);
  bx = nl % gx;
  by = nl / gx;
}
__device__ __forceinline__ int fl_from(const int* cnt) { return cnt[0] > 1800 ? 1 : 0; }
__device__ __forceinline__ int mm_from(const int* cnt) {
  if (cnt[1] == 0)      return (cnt[4] > 0) ? 0 : 1;   // int32 : int64
  if (cnt[2] >= cnt[3]) return 2;                      // uint8
  if (cnt[5] == 0)      return 3;                      // fp32
  return 4;                                            // bf16
}

// ---------------- dtype detection: single block, direct store (no memset needed) ----------------
// Same sampling logic as r1-r15 verified version; 1024 threads cover gid 0..16383 via 16 strides.
__global__ __launch_bounds__(1024) void sa_detect(const void* hs, const void* mask, int* cnt) {
  __shared__ int lc[6];
  if (threadIdx.x < 6) lc[threadIdx.x] = 0;
  __syncthreads();
  int pl = 0, codd = 0, c1 = 0, c3f = 0, c48 = 0, cb1 = 0;
  const unsigned char* mb = (const unsigned char*)mask;
  for (int gid = threadIdx.x; gid < 16384; gid += 1024) {
    if (gid < 2048) {
      unsigned short v = ((const unsigned short*)hs)[2 * gid];
      float f = __uint_as_float(((unsigned)v) << 16);
      float a = fabsf(f);
      if (v == 0 || (a > 1e-9f && a < 1e4f)) pl++;
    }
    #pragma unroll
    for (int r = 0; r < 4; ++r) {
      int i = gid * 4 + r;
      int base = i * 4;
      unsigned char b1 = mb[base + 1], b3 = mb[base + 3];
      if (b1 | b3) codd++;
      if (b1) cb1++;
      if (b1 == 1) c1++;
      if (b3 == 1) c1++;
      if (b1 == 0x3f) c3f++;
      if (b3 == 0x3f) c3f++;
      if (i & 1) { if (mb[base]) c48++; }
    }
  }
  atomicAdd(&lc[0], pl);
  atomicAdd(&lc[1], codd);
  atomicAdd(&lc[2], c1);
  atomicAdd(&lc[3], c3f);
  atomicAdd(&lc[4], c48);
  atomicAdd(&lc[5], cb1);
  __syncthreads();
  if (threadIdx.x < 6) cnt[threadIdx.x] = lc[threadIdx.x];   // direct store: deterministic across replays
}

// ---------------- fused preprocessing (r13-r15 verified): maskexp | Wqkv^T | Wout^T | cvt_hs ----------------
__global__ __launch_bounds__(256) void sa_preproc(const void* mask, u16* m16,
                                                  const void* Wq, u16* WqT,
                                                  const void* Wo, u16* WoT,
                                                  const void* hs, u16* hsb, const int* cnt) {
  int blk = blockIdx.x;
  if (blk < 1024) {
    int idx = blk * 256 + threadIdx.x;
    int i = idx >> 9, c = idx & 511;
    int jw = c >> 5, r = c & 31;
    int g = r >> 3, q = r & 7;
    int t = q >> 2, rr = q & 3;
    long long j = (long long)i * 512 + jw * 32 + t * 16 + 4 * g + rr;
    int mm = mm_from(cnt);
    bool v;
    if      (mm == 0) v = ((const int*)mask)[j] != 0;
    else if (mm == 1) v = ((const long long*)mask)[j] != 0;
    else if (mm == 2) v = ((const unsigned char*)mask)[j] != 0;
    else if (mm == 3) v = ((const float*)mask)[j] != 0.0f;
    else              v = ((const unsigned short*)mask)[j] != 0;
    m16[idx] = v ? 0xFFFFu : 0u;
    return;
  }
  if (blk < 1024 + 1536 + 512) {
    const void* W; u16* WT; int Nld; int idx;
    if (blk < 1024 + 1536) { idx = blk - 1024;        W = Wq; WT = WqT; Nld = QKVC; }
    else                   { idx = blk - 1024 - 1536; W = Wo; WT = WoT; Nld = HH; }
    int xb = idx % (Nld / 256), yb = idx / (Nld / 256);
    int nrow = xb * 256 + threadIdx.x;
    int sc = yb >> 3, u = yb & 7;
    int kb = sc * 64 + u * 8;
    const int fl = fl_from(cnt);
    s16x8 ov;
    #pragma unroll
    for (int e = 0; e < 8; ++e) ov[e] = f2b(load_f(W, (long long)(kb + e) * Nld + nrow, fl));
    *(s16x8*)((char*)WT + (long long)nrow * 2048 + sc * 128 + ((u ^ (nrow & 7)) * 16)) = ov;
    return;
  }
  if (fl_from(cnt)) return;
  int base = blk - (1024 + 1536 + 512);                // 0..511
  for (int it = 0; it < 8; ++it) {
    int tid = (base * 8 + it) * 256 + threadIdx.x;
    int row = tid >> 7, u7 = tid & 127;
    int sc = u7 >> 3, u = u7 & 7;
    long long ebase = (long long)row * 1024 + sc * 64 + u * 8;
    const float4* pf = (const float4*)((const float*)hs + ebase);
    float4 x0 = pf[0], x1 = pf[1];
    s16x8 ov;
    ov[0] = f2b(x0.x); ov[1] = f2b(x0.y); ov[2] = f2b(x0.z); ov[3] = f2b(x0.w);
    ov[4] = f2b(x1.x); ov[5] = f2b(x1.y); ov[6] = f2b(x1.z); ov[7] = f2b(x1.w);
    *(s16x8*)((char*)hsb + (long long)row * 2048 + sc * 128 + ((u ^ (row & 7)) * 16)) = ov;
  }
}

// ---------------- MFMA GEMM 1 (r15-verified; EB padded 264 to kill 4-way bank alias) ----------------
__global__ __launch_bounds__(256) void mm_qkv(const u16* __restrict__ hs, const u16* __restrict__ hsb,
                                              const u16* __restrict__ BT, const void* bias,
                                              u16* qk, u16* V, const int* cnt) {
  __shared__ u16 As[128 * 64];
  __shared__ u16 Bs[128 * 64];
  __shared__ __align__(16) u16 EB[4][264];    // 264: rows offset by 4 banks -> <=2-way (free)
  const int tid = threadIdx.x, w = tid >> 6, lane = tid & 63;
  const int g = lane >> 4, li = lane & 15;
  int bx = blockIdx.x, by = blockIdx.y;
  xcd_swz(bx, by);
  const int m0 = by * 128, n0 = bx * 128;
  const int wm = (w >> 1) * 64, wn = (w & 1) * 64;
  const int K = 1024;
  const int fl = fl_from(cnt);
  f32x4 acc[4][4] = {};
  for (int k0 = 0; k0 < K; k0 += 64) {
    if (k0) __syncthreads();
    #pragma unroll
    for (int q = 0; q < 4; ++q) {
      int c = w * 4 + q;
      int r = c * 8 + (lane >> 3);
      const u16* asrc = fl ? (hs  + (long long)(m0 + r) * K + k0 + (((lane & 7) ^ (r & 7)) * 8))
                           : (hsb + (long long)(m0 + r) * K + k0 + ((lane & 7) * 8));
      gll16(asrc, &As[c * 512]);
      gll16(BT + (long long)(n0 + r) * K + k0 + (lane & 7) * 8, &Bs[c * 512]);
    }
    __syncthreads();
    #pragma unroll
    for (int ks = 0; ks < 2; ++ks) {
      s16x8 af[4], bfr[4];
      #pragma unroll
      for (int mi = 0; mi < 4; ++mi) {
        int r = wm + mi * 16 + li;
        int off = (ks * 64 + g * 16) ^ ((r & 7) << 4);
        af[mi] = *(const s16x8*)((const char*)As + r * 128 + off);
      }
      #pragma unroll
      for (int nj = 0; nj < 4; ++nj) {
        int r = wn + nj * 16 + li;
        int off = (ks * 64 + g * 16) ^ ((r & 7) << 4);
        bfr[nj] = *(const s16x8*)((const char*)Bs + r * 128 + off);
      }
      #pragma unroll
      for (int mi = 0; mi < 4; ++mi)
        #pragma unroll
        for (int nj = 0; nj < 4; ++nj)
          acc[mi][nj] = mfma_bf16(af[mi], bfr[nj], acc[mi][nj]);
    }
  }
  // ---- epilogue (r15-verified): wave purely qk or purely V; LDS bounce -> 128B store runs ----
  const int s0 = (m0 + wm) >> 4;
  const int c16s = (n0 + wn) >> 4;
  const int hts = c16s % 12;                  // 0, 4, or 8
  const int n = c16s / 12;
  u16* eb = &EB[w][0];
  float bvv[4];
  #pragma unroll
  for (int nj = 0; nj < 4; ++nj) bvv[nj] = load_f(bias, n0 + wn + nj * 16 + li, fl);
  if (hts < 8) {
    const long long colb = (long long)n * 128 + hts * 16;
    #pragma unroll
    for (int mi = 0; mi < 4; ++mi)
      #pragma unroll
      for (int rr = 0; rr < 4; ++rr) {
        #pragma unroll
        for (int nj = 0; nj < 4; ++nj)
          eb[g * 64 + nj * 16 + li] = f2b(acc[mi][nj][rr] + bvv[nj]);
        u16x4 pk = *(const u16x4*)(eb + g * 64 + li * 4);
        int b = 4 * g + rr, s = s0 + mi;
        *(u16x4*)(qk + ((long long)(b * 512 + s)) * 2048 + colb + li * 4) = pk;
      }
  } else {
    #pragma unroll
    for (int mi = 0; mi < 4; ++mi)
      #pragma unroll
      for (int rr = 0; rr < 4; ++rr) {
        #pragma unroll
        for (int nj = 0; nj < 4; ++nj)
          eb[g * 64 + nj * 16 + li] = f2b(acc[mi][nj][rr] + bvv[nj]);
        u16x4 pk = *(const u16x4*)(eb + g * 64 + li * 4);
        int bn = (4 * g + rr) * 16 + n, s = s0 + mi;
        *(u16x4*)(V + (long long)bn * 32768 + s * 64 + li * 4) = pk;
      }
  }
}

// ---------------- flash attention v7 (r12-r15 verified, verbatim incl. setprio) ----------------
__global__ __launch_bounds__(1024) void sa_attn7(const u16* __restrict__ qk, const u16* __restrict__ V,
                                                 const u16* __restrict__ m16, u16* __restrict__ ctx) {
  __shared__ __align__(16) u16 SHM[81920];    // Ks 64KB + Vs 64KB + P 32KB = 160KB
  u16* const Ks = SHM;
  u16* const Vs = SHM + 32768;
  u16* const PB = SHM + 65536;

  const int tid = threadIdx.x, w = tid >> 6, lane = tid & 63;
  const int g = lane >> 4, li = lane & 15;
  const int n = blockIdx.x, b = blockIdx.y;

  const u16* kg = qk + (long long)(b * 512) * 2048 + n * 128 + 64;
  #pragma unroll
  for (int it = 0; it < 4; ++it) {
    int lin = it * 1024 + tid;
    int s = lin >> 3, c = lin & 7;
    s16x8 kv = *(const s16x8*)(kg + (long long)s * 2048 + c * 8);
    *(s16x8*)(Ks + s * 64 + ((c ^ (s & 7)) * 8)) = kv;
  }
  const u16* vg = V + (long long)(b * 16 + n) * 32768;
  #pragma unroll
  for (int q = 0; q < 4; ++q) {
    int lin = q * 1024 + tid;
    int s = lin >> 3, dc = lin & 7;
    s16x8 v = *(const s16x8*)(vg + s * 64 + dc * 8);
    #pragma unroll
    for (int e = 0; e < 8; ++e) {
      int d = dc * 8 + e;
      Vs[d * 512 + (((s >> 3) ^ e ^ dc) * 8) + (s & 7)] = v[e];
    }
  }
  __syncthreads();

  const int i0 = w * 32;
  s16x8 qf0[2], qf1[2];
  #pragma unroll
  for (int tl = 0; tl < 2; ++tl) {
    const u16* qb = qk + ((long long)(b * 512 + i0 + tl * 16 + li)) * 2048 + n * 128;
    qf0[tl] = *(const s16x8*)(qb + g * 8);
    qf1[tl] = *(const s16x8*)(qb + 32 + g * 8);
  }
  s16x8 af1;
  #pragma unroll
  for (int e = 0; e < 8; ++e) af1[e] = (li == 0) ? (short)0x3F80 : (short)0;

  char* const pw = (char*)PB + w * 2048;
  const float SC  = 0.125f * 1.44269504f;
  const float THR = 44.3614f;

  const u16* mk0 = m16 + (long long)(i0 + li) * 512 + g * 8;
  const u16* mk1 = m16 + (long long)(i0 + 16 + li) * 512 + g * 8;

  f32x4 cacc[2][4] = {};
  f32x4 lacc[2] = {};
  float m[2] = {-1e30f, -1e30f};

  for (int jw = 0; jw < 16; ++jw) {
    uint4 mmv[2];
    mmv[0] = *(const uint4*)(mk0 + jw * 32);
    mmv[1] = *(const uint4*)(mk1 + jw * 32);
    s16x8 kf0[2], kf1[2];
    #pragma unroll
    for (int t = 0; t < 2; ++t) {
      int j = jw * 32 + t * 16 + li;
      const u16* kb = Ks + j * 64;
      kf0[t] = *(const s16x8*)(kb + ((g ^ (j & 7)) * 8));
      kf1[t] = *(const s16x8*)(kb + (((4 + g) ^ (j & 7)) * 8));
    }
    f32x4 sa[2][2];
    __builtin_amdgcn_s_setprio(1);
    #pragma unroll
    for (int tl = 0; tl < 2; ++tl)
      #pragma unroll
      for (int t = 0; t < 2; ++t) {
        f32x4 z = {};
        z = mfma_bf16(kf0[t], qf0[tl], z);
        z = mfma_bf16(kf1[t], qf1[tl], z);
        sa[tl][t] = z;
      }
    __builtin_amdgcn_s_setprio(0);
    s16x8 pf[2];
    #pragma unroll
    for (int tl = 0; tl < 2; ++tl) {
      float pm = fmaxf(fmaxf(fmaxf(sa[tl][0][0], sa[tl][0][1]), fmaxf(sa[tl][0][2], sa[tl][0][3])),
                       fmaxf(fmaxf(sa[tl][1][0], sa[tl][1][1]), fmaxf(sa[tl][1][2], sa[tl][1][3])));
      pm = fmaxf(pm, __shfl_xor(pm, 16));
      pm = fmaxf(pm, __shfl_xor(pm, 32));
      if (__any(pm > m[tl] + THR)) {
        float mn = fmaxf(m[tl], pm);
        float sc = __builtin_exp2f((m[tl] - mn) * SC);
        lacc[tl] *= sc;
        #pragma unroll
        for (int dt = 0; dt < 4; ++dt) cacc[tl][dt] *= sc;
        m[tl] = mn;
      }
      float mv = m[tl];
      float p0 = __builtin_exp2f((sa[tl][0][0] - mv) * SC);
      float p1 = __builtin_exp2f((sa[tl][0][1] - mv) * SC);
      float p2 = __builtin_exp2f((sa[tl][0][2] - mv) * SC);
      float p3 = __builtin_exp2f((sa[tl][0][3] - mv) * SC);
      float p4 = __builtin_exp2f((sa[tl][1][0] - mv) * SC);
      float p5 = __builtin_exp2f((sa[tl][1][1] - mv) * SC);
      float p6 = __builtin_exp2f((sa[tl][1][2] - mv) * SC);
      float p7 = __builtin_exp2f((sa[tl][1][3] - mv) * SC);
      u32 r0 = cvtpk(p0, p1) & mmv[tl].x;
      u32 r1 = cvtpk(p2, p3) & mmv[tl].y;
      u32 r2 = cvtpk(p4, p5) & mmv[tl].z;
      u32 r3 = cvtpk(p6, p7) & mmv[tl].w;
      char* pt = pw + tl * 1024 + li * 64;
      *(uint2*)(pt + ((g ^ (li & 6)) * 8))       = make_uint2(r0, r1);
      *(uint2*)(pt + (((4 + g) ^ (li & 6)) * 8)) = make_uint2(r2, r3);
      pf[tl] = *(const s16x8*)(pw + tl * 1024 + li * 64 + (((2 * g) ^ (li & 6)) * 8));
      lacc[tl] = mfma_bf16(af1, pf[tl], lacc[tl]);
    }
    __builtin_amdgcn_s_setprio(1);
    #pragma unroll
    for (int dt = 0; dt < 4; ++dt) {
      int d = dt * 16 + li;
      s16x8 vf = *(const s16x8*)(Vs + d * 512 +
                                 (((jw * 4 + g) ^ (d & 7) ^ ((d >> 3) & 7)) * 8));
      #pragma unroll
      for (int tl = 0; tl < 2; ++tl)
        cacc[tl][dt] = mfma_bf16(vf, pf[tl], cacc[tl][dt]);
    }
    __builtin_amdgcn_s_setprio(0);
  }
  #pragma unroll
  for (int tl = 0; tl < 2; ++tl) {
    float lv = __shfl(lacc[tl][0], li);
    float inv = 1.0f / lv;
    #pragma unroll
    for (int dt = 0; dt < 4; ++dt) {
      u32 lo = cvtpk(cacc[tl][dt][0] * inv, cacc[tl][dt][1] * inv);
      u32 hi = cvtpk(cacc[tl][dt][2] * inv, cacc[tl][dt][3] * inv);
      *(uint2*)(pw + li * 128 + (((dt * 4 + g) ^ ((li & 7) << 1)) * 8)) = make_uint2(lo, hi);
    }
    int il = lane >> 2;
    #pragma unroll
    for (int p = 0; p < 2; ++p) {
      int c = (lane & 3) + p * 4;
      s16x8 v = *(const s16x8*)(pw + il * 128 + (((2 * c) ^ ((il & 7) << 1)) * 8));
      *(s16x8*)(ctx + ((long long)((i0 + tl * 16 + il) * 16 + b)) * 1024 + n * 64 +
                ((c ^ (b & 7)) * 8)) = v;
    }
  }
}

// ---------------- MFMA GEMM 2 (r15-verified; EB padded 264) ----------------
__global__ __launch_bounds__(256) void mm_out(const u16* __restrict__ Asrc, const u16* __restrict__ BT,
                                              const void* bias, void* out, const int* cnt) {
  __shared__ u16 As[128 * 64];
  __shared__ u16 Bs[128 * 64];
  __shared__ __align__(16) u16 EB[4][264];
  const int tid = threadIdx.x, w = tid >> 6, lane = tid & 63;
  const int g = lane >> 4, li = lane & 15;
  int bx = blockIdx.x, by = blockIdx.y;
  xcd_swz(bx, by);
  const int m0 = by * 128, n0 = bx * 128;
  const int wm = (w >> 1) * 64, wn = (w & 1) * 64;
  const int K = 1024;
  f32x4 acc[4][4] = {};
  for (int k0 = 0; k0 < K; k0 += 64) {
    if (k0) __syncthreads();
    #pragma unroll
    for (int q = 0; q < 4; ++q) {
      int c = w * 4 + q;
      int r = c * 8 + (lane >> 3);
      gll16(Asrc + (long long)(m0 + r) * K + k0 + (lane & 7) * 8, &As[c * 512]);
      gll16(BT   + (long long)(n0 + r) * K + k0 + (lane & 7) * 8, &Bs[c * 512]);
    }
    __syncthreads();
    #pragma unroll
    for (int ks = 0; ks < 2; ++ks) {
      s16x8 af[4], bfr[4];
      #pragma unroll
      for (int mi = 0; mi < 4; ++mi) {
        int r = wm + mi * 16 + li;
        int off = (ks * 64 + g * 16) ^ ((r & 7) << 4);
        af[mi] = *(const s16x8*)((const char*)As + r * 128 + off);
      }
      #pragma unroll
      for (int nj = 0; nj < 4; ++nj) {
        int r = wn + nj * 16 + li;
        int off = (ks * 64 + g * 16) ^ ((r & 7) << 4);
        bfr[nj] = *(const s16x8*)((const char*)Bs + r * 128 + off);
      }
      #pragma unroll
      for (int mi = 0; mi < 4; ++mi)
        #pragma unroll
        for (int nj = 0; nj < 4; ++nj)
          acc[mi][nj] = mfma_bf16(af[mi], bfr[nj], acc[mi][nj]);
    }
  }
  const int fl = fl_from(cnt);
  u16* eb = &EB[w][0];
  float bvv[4];
  #pragma unroll
  for (int nj = 0; nj < 4; ++nj) bvv[nj] = load_f(bias, n0 + wn + nj * 16 + li, fl);
  if (fl) {
    #pragma unroll
    for (int mi = 0; mi < 4; ++mi)
      #pragma unroll
      for (int rr = 0; rr < 4; ++rr) {
        #pragma unroll
        for (int nj = 0; nj < 4; ++nj)
          eb[g * 64 + nj * 16 + li] = f2b(acc[mi][nj][rr] + bvv[nj]);
        u16x4 pk = *(const u16x4*)(eb + g * 64 + li * 4);
        long long row = m0 + wm + mi * 16 + 4 * g + rr;
        *(u16x4*)((u16*)out + row * 1024 + n0 + wn + li * 4) = pk;
      }
  } else {
    #pragma unroll
    for (int nj = 0; nj < 4; ++nj) {
      int col = n0 + wn + nj * 16 + li;
      #pragma unroll
      for (int mi = 0; mi < 4; ++mi)
        #pragma unroll
        for (int rr = 0; rr < 4; ++rr) {
          long long row = m0 + wm + mi * 16 + 4 * g + rr;
          ((float*)out)[row * 1024 + col] = acc[mi][nj][rr] + bvv[nj];
        }
    }
  }
}

extern "C" void kernel_launch(void* const* d_in, const int* in_sizes, int n_in,
                              void* d_out, int out_size, void* d_ws, size_t ws_size,
                              hipStream_t stream) {
  const void* hs   = d_in[0];
  const void* mask = d_in[1];
  const void* Wqkv = d_in[2];
  const void* bqkv = d_in[3];
  const void* Wout = d_in[4];
  const void* bout = d_in[5];

  char* ws = (char*)d_ws;
  int* cnt   = (int*)(ws + 64);
  u16* m16   = (u16*)(ws + OFF_M16);
  u16* WqkvT = (u16*)(ws + OFF_WQT);
  u16* WoutT = (u16*)(ws + OFF_WOT);
  u16* qk    = (u16*)(ws + OFF_QK);
  u16* V     = (u16*)(ws + OFF_VT);
  u16* ctx   = (u16*)(ws + OFF_CTX);
  u16* hsb   = ctx;   // aliased; used only in fp32 fallback, dead before ctx written

  sa_detect<<<1, 1024, 0, stream>>>(hs, mask, cnt);
  // fused preproc: [0,1024) maskexp | [1024,2560) WqkvT | [2560,3072) WoutT | [3072,3584) cvt_hs
  sa_preproc<<<3584, 256, 0, stream>>>(mask, m16, Wqkv, WqkvT, Wout, WoutT, hs, hsb, cnt);

  mm_qkv<<<dim3(QKVC / 128, ROWS / 128), 256, 0, stream>>>(
      (const u16*)hs, hsb, WqkvT, bqkv, qk, V, cnt);
  sa_attn7<<<dim3(NHEAD, BB), 1024, 0, stream>>>(qk, V, m16, ctx);
  mm_out<<<dim3(HH / 128, ROWS / 128), 256, 0, stream>>>(ctx, WoutT, bout, d_out, cnt);
}

// Round 17
// 167.043 us; speedup vs baseline: 1.1487x; 1.1487x over previous
//
#include <hip/hip_runtime.h>
#include <hip/hip_bf16.h>

typedef __hip_bfloat16 bf16;
typedef unsigned short u16;
typedef unsigned int u32;
typedef unsigned long long u64;
typedef float f32x4 __attribute__((ext_vector_type(4)));
typedef short s16x8 __attribute__((ext_vector_type(8)));
typedef unsigned short u16x4 __attribute__((ext_vector_type(4)));

static constexpr int SQ    = 512;
static constexpr int BB    = 16;
static constexpr int HH    = 1024;
static constexpr int NHEAD = 16;
static constexpr int ROWS  = SQ * BB;        // 8192
static constexpr int QKVC  = 3 * HH;         // 3072

// ---- ws layout (bytes) ----
static constexpr long long OFF_M16   = 4096;     // 512KB expanded mask
static constexpr long long OFF_WQT   = 1048576;
static constexpr long long OFF_WOT   = OFF_WQT + (long long)QKVC * HH * 2;
static constexpr long long OFF_QK    = OFF_WOT + (long long)HH * HH * 2;
static constexpr long long OFF_VT    = OFF_QK + (long long)ROWS * 2048 * 2;
static constexpr long long OFF_CTX   = OFF_VT + (long long)256 * 64 * 512 * 2;

__device__ __forceinline__ float load_f(const void* p, long long i, int is_bf16) {
  if (is_bf16) return __bfloat162float(((const bf16*)p)[i]);
  return ((const float*)p)[i];
}
__device__ __forceinline__ u16 f2b(float x) { bf16 h = __float2bfloat16(x); return *(u16*)&h; }
__device__ __forceinline__ f32x4 mfma_bf16(s16x8 a, s16x8 b, f32x4 c) {
  return __builtin_amdgcn_mfma_f32_16x16x32_bf16(a, b, c, 0, 0, 0);
}
__device__ __forceinline__ void gll16(const void* g, void* lds) {
  __builtin_amdgcn_global_load_lds((const __attribute__((address_space(1))) unsigned int*)g,
                                   (__attribute__((address_space(3))) unsigned int*)lds, 16, 0, 0);
}
__device__ __forceinline__ u32 cvtpk(float lo, float hi) {
  u32 r;
  asm volatile("v_cvt_pk_bf16_f32 %0, %1, %2" : "=v"(r) : "v"(lo), "v"(hi));
  return r;
}
// bijective XCD-aware block swizzle (live-verified r6-r16)
__device__ __forceinline__ void xcd_swz(int& bx, int& by) {
  int gx = gridDim.x;
  int nw = gx * gridDim.y;
  int lin = by * gx + bx;
  int q = nw >> 3;
  int nl = (lin & 7) * q + (lin >> 3);
  bx = nl % gx;
  by = nl / gx;
}
__device__ __forceinline__ int fl_from(const int* cnt) { return cnt[0] > 1800 ? 1 : 0; }
__device__ __forceinline__ int mm_from(const int* cnt) {
  if (cnt[1] == 0)      return (cnt[4] > 0) ? 0 : 1;   // int32 : int64
  if (cnt[2] >= cnt[3]) return 2;                      // uint8
  if (cnt[5] == 0)      return 3;                      // fp32
  return 4;                                            // bf16
}

// ---------------- dtype detection (r15-verified 64-block form; single-block r16 REGRESSED, reverted) ----------------
__global__ __launch_bounds__(256) void sa_detect_part(const void* hs, const void* mask, int* cnt) {
  __shared__ int lc[6];
  if (threadIdx.x < 6) lc[threadIdx.x] = 0;
  __syncthreads();
  int gid = blockIdx.x * 256 + threadIdx.x;
  if (gid < 2048) {
    unsigned short v = ((const unsigned short*)hs)[2 * gid];
    float f = __uint_as_float(((unsigned)v) << 16);
    float a = fabsf(f);
    if (v == 0 || (a > 1e-9f && a < 1e4f)) atomicAdd(&lc[0], 1);
  }
  const unsigned char* mb = (const unsigned char*)mask;
  int codd = 0, c1 = 0, c3f = 0, c48 = 0, cb1 = 0;
  #pragma unroll
  for (int r = 0; r < 4; ++r) {
    int i = gid * 4 + r;
    int base = i * 4;
    unsigned char b1 = mb[base + 1], b3 = mb[base + 3];
    if (b1 | b3) codd++;
    if (b1) cb1++;
    if (b1 == 1) c1++;
    if (b3 == 1) c1++;
    if (b1 == 0x3f) c3f++;
    if (b3 == 0x3f) c3f++;
    if (i & 1) { if (mb[base]) c48++; }
  }
  atomicAdd(&lc[1], codd);
  atomicAdd(&lc[2], c1);
  atomicAdd(&lc[3], c3f);
  atomicAdd(&lc[4], c48);
  atomicAdd(&lc[5], cb1);
  __syncthreads();
  if (threadIdx.x < 6) atomicAdd(&cnt[threadIdx.x], lc[threadIdx.x]);
}

// ---------------- fused preprocessing (r13-r16 verified): maskexp | Wqkv^T | Wout^T | cvt_hs ----------------
__global__ __launch_bounds__(256) void sa_preproc(const void* mask, u16* m16,
                                                  const void* Wq, u16* WqT,
                                                  const void* Wo, u16* WoT,
                                                  const void* hs, u16* hsb, const int* cnt) {
  int blk = blockIdx.x;
  if (blk < 1024) {
    int idx = blk * 256 + threadIdx.x;
    int i = idx >> 9, c = idx & 511;
    int jw = c >> 5, r = c & 31;
    int g = r >> 3, q = r & 7;
    int t = q >> 2, rr = q & 3;
    long long j = (long long)i * 512 + jw * 32 + t * 16 + 4 * g + rr;
    int mm = mm_from(cnt);
    bool v;
    if      (mm == 0) v = ((const int*)mask)[j] != 0;
    else if (mm == 1) v = ((const long long*)mask)[j] != 0;
    else if (mm == 2) v = ((const unsigned char*)mask)[j] != 0;
    else if (mm == 3) v = ((const float*)mask)[j] != 0.0f;
    else              v = ((const unsigned short*)mask)[j] != 0;
    m16[idx] = v ? 0xFFFFu : 0u;
    return;
  }
  if (blk < 1024 + 1536 + 512) {
    const void* W; u16* WT; int Nld; int idx;
    if (blk < 1024 + 1536) { idx = blk - 1024;        W = Wq; WT = WqT; Nld = QKVC; }
    else                   { idx = blk - 1024 - 1536; W = Wo; WT = WoT; Nld = HH; }
    int xb = idx % (Nld / 256), yb = idx / (Nld / 256);
    int nrow = xb * 256 + threadIdx.x;
    int sc = yb >> 3, u = yb & 7;
    int kb = sc * 64 + u * 8;
    const int fl = fl_from(cnt);
    s16x8 ov;
    #pragma unroll
    for (int e = 0; e < 8; ++e) ov[e] = f2b(load_f(W, (long long)(kb + e) * Nld + nrow, fl));
    *(s16x8*)((char*)WT + (long long)nrow * 2048 + sc * 128 + ((u ^ (nrow & 7)) * 16)) = ov;
    return;
  }
  if (fl_from(cnt)) return;
  int base = blk - (1024 + 1536 + 512);                // 0..511
  for (int it = 0; it < 8; ++it) {
    int tid = (base * 8 + it) * 256 + threadIdx.x;
    int row = tid >> 7, u7 = tid & 127;
    int sc = u7 >> 3, u = u7 & 7;
    long long ebase = (long long)row * 1024 + sc * 64 + u * 8;
    const float4* pf = (const float4*)((const float*)hs + ebase);
    float4 x0 = pf[0], x1 = pf[1];
    s16x8 ov;
    ov[0] = f2b(x0.x); ov[1] = f2b(x0.y); ov[2] = f2b(x0.z); ov[3] = f2b(x0.w);
    ov[4] = f2b(x1.x); ov[5] = f2b(x1.y); ov[6] = f2b(x1.z); ov[7] = f2b(x1.w);
    *(s16x8*)((char*)hsb + (long long)row * 2048 + sc * 128 + ((u ^ (row & 7)) * 16)) = ov;
  }
}

// ---------------- MFMA GEMM 1 (r15/r16-verified) ----------------
__global__ __launch_bounds__(256) void mm_qkv(const u16* __restrict__ hs, const u16* __restrict__ hsb,
                                              const u16* __restrict__ BT, const void* bias,
                                              u16* qk, u16* V, const int* cnt) {
  __shared__ u16 As[128 * 64];
  __shared__ u16 Bs[128 * 64];
  __shared__ __align__(16) u16 EB[4][264];
  const int tid = threadIdx.x, w = tid >> 6, lane = tid & 63;
  const int g = lane >> 4, li = lane & 15;
  int bx = blockIdx.x, by = blockIdx.y;
  xcd_swz(bx, by);
  const int m0 = by * 128, n0 = bx * 128;
  const int wm = (w >> 1) * 64, wn = (w & 1) * 64;
  const int K = 1024;
  const int fl = fl_from(cnt);
  f32x4 acc[4][4] = {};
  for (int k0 = 0; k0 < K; k0 += 64) {
    if (k0) __syncthreads();
    #pragma unroll
    for (int q = 0; q < 4; ++q) {
      int c = w * 4 + q;
      int r = c * 8 + (lane >> 3);
      const u16* asrc = fl ? (hs  + (long long)(m0 + r) * K + k0 + (((lane & 7) ^ (r & 7)) * 8))
                           : (hsb + (long long)(m0 + r) * K + k0 + ((lane & 7) * 8));
      gll16(asrc, &As[c * 512]);
      gll16(BT + (long long)(n0 + r) * K + k0 + (lane & 7) * 8, &Bs[c * 512]);
    }
    __syncthreads();
    #pragma unroll
    for (int ks = 0; ks < 2; ++ks) {
      s16x8 af[4], bfr[4];
      #pragma unroll
      for (int mi = 0; mi < 4; ++mi) {
        int r = wm + mi * 16 + li;
        int off = (ks * 64 + g * 16) ^ ((r & 7) << 4);
        af[mi] = *(const s16x8*)((const char*)As + r * 128 + off);
      }
      #pragma unroll
      for (int nj = 0; nj < 4; ++nj) {
        int r = wn + nj * 16 + li;
        int off = (ks * 64 + g * 16) ^ ((r & 7) << 4);
        bfr[nj] = *(const s16x8*)((const char*)Bs + r * 128 + off);
      }
      #pragma unroll
      for (int mi = 0; mi < 4; ++mi)
        #pragma unroll
        for (int nj = 0; nj < 4; ++nj)
          acc[mi][nj] = mfma_bf16(af[mi], bfr[nj], acc[mi][nj]);
    }
  }
  const int s0 = (m0 + wm) >> 4;
  const int c16s = (n0 + wn) >> 4;
  const int hts = c16s % 12;
  const int n = c16s / 12;
  u16* eb = &EB[w][0];
  float bvv[4];
  #pragma unroll
  for (int nj = 0; nj < 4; ++nj) bvv[nj] = load_f(bias, n0 + wn + nj * 16 + li, fl);
  if (hts < 8) {
    const long long colb = (long long)n * 128 + hts * 16;
    #pragma unroll
    for (int mi = 0; mi < 4; ++mi)
      #pragma unroll
      for (int rr = 0; rr < 4; ++rr) {
        #pragma unroll
        for (int nj = 0; nj < 4; ++nj)
          eb[g * 64 + nj * 16 + li] = f2b(acc[mi][nj][rr] + bvv[nj]);
        u16x4 pk = *(const u16x4*)(eb + g * 64 + li * 4);
        int b = 4 * g + rr, s = s0 + mi;
        *(u16x4*)(qk + ((long long)(b * 512 + s)) * 2048 + colb + li * 4) = pk;
      }
  } else {
    #pragma unroll
    for (int mi = 0; mi < 4; ++mi)
      #pragma unroll
      for (int rr = 0; rr < 4; ++rr) {
        #pragma unroll
        for (int nj = 0; nj < 4; ++nj)
          eb[g * 64 + nj * 16 + li] = f2b(acc[mi][nj][rr] + bvv[nj]);
        u16x4 pk = *(const u16x4*)(eb + g * 64 + li * 4);
        int bn = (4 * g + rr) * 16 + n, s = s0 + mi;
        *(u16x4*)(V + (long long)bn * 32768 + s * 64 + li * 4) = pk;
      }
  }
}

// ---------------- flash attention v7 (r12-r16 verified, verbatim incl. setprio) ----------------
__global__ __launch_bounds__(1024) void sa_attn7(const u16* __restrict__ qk, const u16* __restrict__ V,
                                                 const u16* __restrict__ m16, u16* __restrict__ ctx) {
  __shared__ __align__(16) u16 SHM[81920];    // Ks 64KB + Vs 64KB + P 32KB = 160KB
  u16* const Ks = SHM;
  u16* const Vs = SHM + 32768;
  u16* const PB = SHM + 65536;

  const int tid = threadIdx.x, w = tid >> 6, lane = tid & 63;
  const int g = lane >> 4, li = lane & 15;
  const int n = blockIdx.x, b = blockIdx.y;

  const u16* kg = qk + (long long)(b * 512) * 2048 + n * 128 + 64;
  #pragma unroll
  for (int it = 0; it < 4; ++it) {
    int lin = it * 1024 + tid;
    int s = lin >> 3, c = lin & 7;
    s16x8 kv = *(const s16x8*)(kg + (long long)s * 2048 + c * 8);
    *(s16x8*)(Ks + s * 64 + ((c ^ (s & 7)) * 8)) = kv;
  }
  const u16* vg = V + (long long)(b * 16 + n) * 32768;
  #pragma unroll
  for (int q = 0; q < 4; ++q) {
    int lin = q * 1024 + tid;
    int s = lin >> 3, dc = lin & 7;
    s16x8 v = *(const s16x8*)(vg + s * 64 + dc * 8);
    #pragma unroll
    for (int e = 0; e < 8; ++e) {
      int d = dc * 8 + e;
      Vs[d * 512 + (((s >> 3) ^ e ^ dc) * 8) + (s & 7)] = v[e];
    }
  }
  __syncthreads();

  const int i0 = w * 32;
  s16x8 qf0[2], qf1[2];
  #pragma unroll
  for (int tl = 0; tl < 2; ++tl) {
    const u16* qb = qk + ((long long)(b * 512 + i0 + tl * 16 + li)) * 2048 + n * 128;
    qf0[tl] = *(const s16x8*)(qb + g * 8);
    qf1[tl] = *(const s16x8*)(qb + 32 + g * 8);
  }
  s16x8 af1;
  #pragma unroll
  for (int e = 0; e < 8; ++e) af1[e] = (li == 0) ? (short)0x3F80 : (short)0;

  char* const pw = (char*)PB + w * 2048;
  const float SC  = 0.125f * 1.44269504f;
  const float THR = 44.3614f;

  const u16* mk0 = m16 + (long long)(i0 + li) * 512 + g * 8;
  const u16* mk1 = m16 + (long long)(i0 + 16 + li) * 512 + g * 8;

  f32x4 cacc[2][4] = {};
  f32x4 lacc[2] = {};
  float m[2] = {-1e30f, -1e30f};

  for (int jw = 0; jw < 16; ++jw) {
    uint4 mmv[2];
    mmv[0] = *(const uint4*)(mk0 + jw * 32);
    mmv[1] = *(const uint4*)(mk1 + jw * 32);
    s16x8 kf0[2], kf1[2];
    #pragma unroll
    for (int t = 0; t < 2; ++t) {
      int j = jw * 32 + t * 16 + li;
      const u16* kb = Ks + j * 64;
      kf0[t] = *(const s16x8*)(kb + ((g ^ (j & 7)) * 8));
      kf1[t] = *(const s16x8*)(kb + (((4 + g) ^ (j & 7)) * 8));
    }
    f32x4 sa[2][2];
    __builtin_amdgcn_s_setprio(1);
    #pragma unroll
    for (int tl = 0; tl < 2; ++tl)
      #pragma unroll
      for (int t = 0; t < 2; ++t) {
        f32x4 z = {};
        z = mfma_bf16(kf0[t], qf0[tl], z);
        z = mfma_bf16(kf1[t], qf1[tl], z);
        sa[tl][t] = z;
      }
    __builtin_amdgcn_s_setprio(0);
    s16x8 pf[2];
    #pragma unroll
    for (int tl = 0; tl < 2; ++tl) {
      float pm = fmaxf(fmaxf(fmaxf(sa[tl][0][0], sa[tl][0][1]), fmaxf(sa[tl][0][2], sa[tl][0][3])),
                       fmaxf(fmaxf(sa[tl][1][0], sa[tl][1][1]), fmaxf(sa[tl][1][2], sa[tl][1][3])));
      pm = fmaxf(pm, __shfl_xor(pm, 16));
      pm = fmaxf(pm, __shfl_xor(pm, 32));
      if (__any(pm > m[tl] + THR)) {
        float mn = fmaxf(m[tl], pm);
        float sc = __builtin_exp2f((m[tl] - mn) * SC);
        lacc[tl] *= sc;
        #pragma unroll
        for (int dt = 0; dt < 4; ++dt) cacc[tl][dt] *= sc;
        m[tl] = mn;
      }
      float mv = m[tl];
      float p0 = __builtin_exp2f((sa[tl][0][0] - mv) * SC);
      float p1 = __builtin_exp2f((sa[tl][0][1] - mv) * SC);
      float p2 = __builtin_exp2f((sa[tl][0][2] - mv) * SC);
      float p3 = __builtin_exp2f((sa[tl][0][3] - mv) * SC);
      float p4 = __builtin_exp2f((sa[tl][1][0] - mv) * SC);
      float p5 = __builtin_exp2f((sa[tl][1][1] - mv) * SC);
      float p6 = __builtin_exp2f((sa[tl][1][2] - mv) * SC);
      float p7 = __builtin_exp2f((sa[tl][1][3] - mv) * SC);
      u32 r0 = cvtpk(p0, p1) & mmv[tl].x;
      u32 r1 = cvtpk(p2, p3) & mmv[tl].y;
      u32 r2 = cvtpk(p4, p5) & mmv[tl].z;
      u32 r3 = cvtpk(p6, p7) & mmv[tl].w;
      char* pt = pw + tl * 1024 + li * 64;
      *(uint2*)(pt + ((g ^ (li & 6)) * 8))       = make_uint2(r0, r1);
      *(uint2*)(pt + (((4 + g) ^ (li & 6)) * 8)) = make_uint2(r2, r3);
      pf[tl] = *(const s16x8*)(pw + tl * 1024 + li * 64 + (((2 * g) ^ (li & 6)) * 8));
      lacc[tl] = mfma_bf16(af1, pf[tl], lacc[tl]);
    }
    __builtin_amdgcn_s_setprio(1);
    #pragma unroll
    for (int dt = 0; dt < 4; ++dt) {
      int d = dt * 16 + li;
      s16x8 vf = *(const s16x8*)(Vs + d * 512 +
                                 (((jw * 4 + g) ^ (d & 7) ^ ((d >> 3) & 7)) * 8));
      #pragma unroll
      for (int tl = 0; tl < 2; ++tl)
        cacc[tl][dt] = mfma_bf16(vf, pf[tl], cacc[tl][dt]);
    }
    __builtin_amdgcn_s_setprio(0);
  }
  #pragma unroll
  for (int tl = 0; tl < 2; ++tl) {
    float lv = __shfl(lacc[tl][0], li);
    float inv = 1.0f / lv;
    #pragma unroll
    for (int dt = 0; dt < 4; ++dt) {
      u32 lo = cvtpk(cacc[tl][dt][0] * inv, cacc[tl][dt][1] * inv);
      u32 hi = cvtpk(cacc[tl][dt][2] * inv, cacc[tl][dt][3] * inv);
      *(uint2*)(pw + li * 128 + (((dt * 4 + g) ^ ((li & 7) << 1)) * 8)) = make_uint2(lo, hi);
    }
    int il = lane >> 2;
    #pragma unroll
    for (int p = 0; p < 2; ++p) {
      int c = (lane & 3) + p * 4;
      s16x8 v = *(const s16x8*)(pw + il * 128 + (((2 * c) ^ ((il & 7) << 1)) * 8));
      *(s16x8*)(ctx + ((long long)((i0 + tl * 16 + il) * 16 + b)) * 1024 + n * 64 +
                ((c ^ (b & 7)) * 8)) = v;
    }
  }
}

// ---------------- MFMA GEMM 2 (r15/r16-verified) ----------------
__global__ __launch_bounds__(256) void mm_out(const u16* __restrict__ Asrc, const u16* __restrict__ BT,
                                              const void* bias, void* out, const int* cnt) {
  __shared__ u16 As[128 * 64];
  __shared__ u16 Bs[128 * 64];
  __shared__ __align__(16) u16 EB[4][264];
  const int tid = threadIdx.x, w = tid >> 6, lane = tid & 63;
  const int g = lane >> 4, li = lane & 15;
  int bx = blockIdx.x, by = blockIdx.y;
  xcd_swz(bx, by);
  const int m0 = by * 128, n0 = bx * 128;
  const int wm = (w >> 1) * 64, wn = (w & 1) * 64;
  const int K = 1024;
  f32x4 acc[4][4] = {};
  for (int k0 = 0; k0 < K; k0 += 64) {
    if (k0) __syncthreads();
    #pragma unroll
    for (int q = 0; q < 4; ++q) {
      int c = w * 4 + q;
      int r = c * 8 + (lane >> 3);
      gll16(Asrc + (long long)(m0 + r) * K + k0 + (lane & 7) * 8, &As[c * 512]);
      gll16(BT   + (long long)(n0 + r) * K + k0 + (lane & 7) * 8, &Bs[c * 512]);
    }
    __syncthreads();
    #pragma unroll
    for (int ks = 0; ks < 2; ++ks) {
      s16x8 af[4], bfr[4];
      #pragma unroll
      for (int mi = 0; mi < 4; ++mi) {
        int r = wm + mi * 16 + li;
        int off = (ks * 64 + g * 16) ^ ((r & 7) << 4);
        af[mi] = *(const s16x8*)((const char*)As + r * 128 + off);
      }
      #pragma unroll
      for (int nj = 0; nj < 4; ++nj) {
        int r = wn + nj * 16 + li;
        int off = (ks * 64 + g * 16) ^ ((r & 7) << 4);
        bfr[nj] = *(const s16x8*)((const char*)Bs + r * 128 + off);
      }
      #pragma unroll
      for (int mi = 0; mi < 4; ++mi)
        #pragma unroll
        for (int nj = 0; nj < 4; ++nj)
          acc[mi][nj] = mfma_bf16(af[mi], bfr[nj], acc[mi][nj]);
    }
  }
  const int fl = fl_from(cnt);
  u16* eb = &EB[w][0];
  float bvv[4];
  #pragma unroll
  for (int nj = 0; nj < 4; ++nj) bvv[nj] = load_f(bias, n0 + wn + nj * 16 + li, fl);
  if (fl) {
    #pragma unroll
    for (int mi = 0; mi < 4; ++mi)
      #pragma unroll
      for (int rr = 0; rr < 4; ++rr) {
        #pragma unroll
        for (int nj = 0; nj < 4; ++nj)
          eb[g * 64 + nj * 16 + li] = f2b(acc[mi][nj][rr] + bvv[nj]);
        u16x4 pk = *(const u16x4*)(eb + g * 64 + li * 4);
        long long row = m0 + wm + mi * 16 + 4 * g + rr;
        *(u16x4*)((u16*)out + row * 1024 + n0 + wn + li * 4) = pk;
      }
  } else {
    #pragma unroll
    for (int nj = 0; nj < 4; ++nj) {
      int col = n0 + wn + nj * 16 + li;
      #pragma unroll
      for (int mi = 0; mi < 4; ++mi)
        #pragma unroll
        for (int rr = 0; rr < 4; ++rr) {
          long long row = m0 + wm + mi * 16 + 4 * g + rr;
          ((float*)out)[row * 1024 + col] = acc[mi][nj][rr] + bvv[nj];
        }
    }
  }
}

extern "C" void kernel_launch(void* const* d_in, const int* in_sizes, int n_in,
                              void* d_out, int out_size, void* d_ws, size_t ws_size,
                              hipStream_t stream) {
  const void* hs   = d_in[0];
  const void* mask = d_in[1];
  const void* Wqkv = d_in[2];
  const void* bqkv = d_in[3];
  const void* Wout = d_in[4];
  const void* bout = d_in[5];

  char* ws = (char*)d_ws;
  int* cnt   = (int*)(ws + 64);
  u16* m16   = (u16*)(ws + OFF_M16);
  u16* WqkvT = (u16*)(ws + OFF_WQT);
  u16* WoutT = (u16*)(ws + OFF_WOT);
  u16* qk    = (u16*)(ws + OFF_QK);
  u16* V     = (u16*)(ws + OFF_VT);
  u16* ctx   = (u16*)(ws + OFF_CTX);
  u16* hsb   = ctx;   // aliased; used only in fp32 fallback, dead before ctx written

  hipMemsetAsync(cnt, 0, 64, stream);
  sa_detect_part<<<64, 256, 0, stream>>>(hs, mask, cnt);
  // fused preproc: [0,1024) maskexp | [1024,2560) WqkvT | [2560,3072) WoutT | [3072,3584) cvt_hs
  sa_preproc<<<3584, 256, 0, stream>>>(mask, m16, Wqkv, WqkvT, Wout, WoutT, hs, hsb, cnt);

  mm_qkv<<<dim3(QKVC / 128, ROWS / 128), 256, 0, stream>>>(
      (const u16*)hs, hsb, WqkvT, bqkv, qk, V, cnt);
  sa_attn7<<<dim3(NHEAD, BB), 1024, 0, stream>>>(qk, V, m16, ctx);
  mm_out<<<dim3(HH / 128, ROWS / 128), 256, 0, stream>>>(ctx, WoutT, bout, d_out, cnt);
}